// Round 1
// baseline (50.533 us; speedup 1.0000x reference)
//
#include <hip/hip_runtime.h>
#include <hip/hip_bf16.h>

// out = leaky( rowscale(adj) @ X @ W^T + b ),  B=16, N=1024, F_IN=F_OUT=128
// Reassociated: Y = X @ W^T  (kernel 1, writes Y^T bf16 to ws)
//               out = invdeg * (adj @ Y) + b, leaky  (kernel 2, fused)

typedef __attribute__((ext_vector_type(8))) __bf16 bf16x8;
typedef __attribute__((ext_vector_type(4))) float f32x4;

// round-to-nearest-even fp32 -> bf16 (finite inputs), packed pair into u32
__device__ __forceinline__ unsigned f2bf_pk(float lo, float hi) {
    union { float f; unsigned u; } a, b;
    a.f = lo; b.f = hi;
    unsigned ra = (a.u + 0x7FFFu + ((a.u >> 16) & 1u)) >> 16;
    unsigned rb = (b.u + 0x7FFFu + ((b.u >> 16) & 1u)) & 0xFFFF0000u;
    return ra | rb;
}

// ---------------- Kernel 1: Y^T[b][o][m] = sum_f X[b][m][f] * W[o][f] ----------------
// grid 512 (16 batches x 32 row-blocks of 32), block 256 (4 waves, 2x2 wave tiles 16x64)
__global__ __launch_bounds__(256, 2)
void k1_xw(const float* __restrict__ x, const float* __restrict__ W,
           unsigned short* __restrict__ yT)
{
    __shared__ unsigned short Ax[32 * 128];   // X tile [m][f] bf16, rows 256B, swizzled
    __shared__ unsigned short Bw[128 * 128];  // W      [o][f] bf16, rows 256B, swizzled

    const int t  = threadIdx.x;
    const int wg = blockIdx.x;
    const int b  = wg >> 5;
    const int m0 = (wg & 31) << 5;
    const float* xb = x + (((long)b << 10) + m0) * 128;

    // stage X tile (32x128 fp32 -> bf16), flat coalesced, swizzled ds_write
#pragma unroll
    for (int i = 0; i < 4; ++i) {
        int e = i * 1024 + t * 4;
        int r = e >> 7, f = e & 127;
        f32x4 v = *(const f32x4*)(xb + (long)r * 128 + f);
        int c = f >> 3;
        int byte = r * 256 + (((c ^ (r & 7)) << 4) | ((f & 7) << 1));
        uint2 pk; pk.x = f2bf_pk(v.x, v.y); pk.y = f2bf_pk(v.z, v.w);
        *(uint2*)((char*)Ax + byte) = pk;
    }
    // stage full W (128x128 fp32 -> bf16)
#pragma unroll
    for (int i = 0; i < 16; ++i) {
        int e = i * 1024 + t * 4;
        int r = e >> 7, f = e & 127;
        f32x4 v = *(const f32x4*)(W + r * 128 + f);
        int c = f >> 3;
        int byte = r * 256 + (((c ^ (r & 7)) << 4) | ((f & 7) << 1));
        uint2 pk; pk.x = f2bf_pk(v.x, v.y); pk.y = f2bf_pk(v.z, v.w);
        *(uint2*)((char*)Bw + byte) = pk;
    }
    __syncthreads();

    const int lane = t & 63, w = t >> 6;
    const int wm = w >> 1, wn = w & 1;
    const int lrow = lane & 15, lq = lane >> 4;

    // A fragments: row = wm*16 + lrow, k-chunk = kk*4 + lq  (k = 8 contiguous f)
    bf16x8 af[4];
#pragma unroll
    for (int kk = 0; kk < 4; ++kk) {
        int r = wm * 16 + lrow;
        int c = kk * 4 + lq;
        af[kk] = *(const bf16x8*)((const char*)Ax + r * 256 + ((c ^ (r & 7)) << 4));
    }

    f32x4 zero = {0.f, 0.f, 0.f, 0.f};
    f32x4 acc[4] = {zero, zero, zero, zero};
#pragma unroll
    for (int nf = 0; nf < 4; ++nf) {
#pragma unroll
        for (int kk = 0; kk < 4; ++kk) {
            int o = wn * 64 + nf * 16 + lrow;
            int c = kk * 4 + lq;
            bf16x8 bfrag = *(const bf16x8*)((const char*)Bw + o * 256 + ((c ^ (o & 7)) << 4));
            acc[nf] = __builtin_amdgcn_mfma_f32_16x16x32_bf16(af[kk], bfrag, acc[nf], 0, 0, 0);
        }
    }

    // write Y^T: lane holds rows mb..mb+3 (contiguous in Y^T) for col o -> one 8B store
#pragma unroll
    for (int nf = 0; nf < 4; ++nf) {
        int o  = wn * 64 + nf * 16 + lrow;
        int mb = m0 + wm * 16 + lq * 4;
        uint2 pk;
        pk.x = f2bf_pk(acc[nf][0], acc[nf][1]);
        pk.y = f2bf_pk(acc[nf][2], acc[nf][3]);
        *(uint2*)(yT + (((long)b * 128 + o) << 10) + mb) = pk;
    }
}

// ---------------- Kernel 2: out = leaky( invdeg * (adj @ Y) + bias ) ----------------
// grid 512 (16 batches x 32 row-blocks of 32), block 256 (4 waves, 2x2 wave tiles 16x64)
// K loop over m (1024) in steps of 64. Degrees accumulated in fp32 during adj staging.
__global__ __launch_bounds__(256, 2)
void k2_agg(const float* __restrict__ adj, const unsigned short* __restrict__ yT,
            const float* __restrict__ bias, float* __restrict__ out)
{
    __shared__ unsigned short Aa[32 * 64];    // adj tile bf16 [n][m], rows 128B, swizzled
    __shared__ unsigned short By[128 * 64];   // Y^T tile     [o][m], rows 128B, swizzled
    __shared__ float psums[512];
    __shared__ float invdeg[32];

    const int t  = threadIdx.x;
    const int wg = blockIdx.x;
    const int b  = wg >> 5;
    const int n0 = (wg & 31) << 5;
    const float* adjb = adj + ((long)(b * 1024 + n0)) * 1024;
    const unsigned short* yTb = yT + ((long)b << 17);  // b * 128 * 1024

    const int lane = t & 63, w = t >> 6;
    const int wm = w >> 1, wn = w & 1;
    const int lrow = lane & 15, lq = lane >> 4;

    float ps0 = 0.f, ps1 = 0.f;
    f32x4 zero = {0.f, 0.f, 0.f, 0.f};
    f32x4 acc[4] = {zero, zero, zero, zero};

    for (int k0 = 0; k0 < 1024; k0 += 64) {
        // ---- stage adj tile (32x64 fp32): flat coalesced, fp32 row-sum, bf16 swizzled write
        {
            int e = t * 4;
            int r = e >> 6, f = e & 63;
            f32x4 v = *(const f32x4*)(adjb + (long)r * 1024 + k0 + f);
            ps0 += v.x + v.y + v.z + v.w;
            int byte = r * 128 + (((f >> 3) ^ (r & 7)) << 4) + ((f & 7) << 1);
            uint2 pk; pk.x = f2bf_pk(v.x, v.y); pk.y = f2bf_pk(v.z, v.w);
            *(uint2*)((char*)Aa + byte) = pk;

            e = 1024 + t * 4;
            r = e >> 6; f = e & 63;
            v = *(const f32x4*)(adjb + (long)r * 1024 + k0 + f);
            ps1 += v.x + v.y + v.z + v.w;
            byte = r * 128 + (((f >> 3) ^ (r & 7)) << 4) + ((f & 7) << 1);
            pk.x = f2bf_pk(v.x, v.y); pk.y = f2bf_pk(v.z, v.w);
            *(uint2*)((char*)Aa + byte) = pk;
        }
        // ---- stage Y^T tile (128 rows x 64 m bf16): coalesced 16B loads, swizzled write
#pragma unroll
        for (int i = 0; i < 4; ++i) {
            int chunk = i * 256 + t;
            int r = chunk >> 3, c = chunk & 7;
            uint4 v = *(const uint4*)(yTb + (long)r * 1024 + k0 + c * 8);
            *(uint4*)((char*)By + r * 128 + ((c ^ (r & 7)) << 4)) = v;
        }
        __syncthreads();

        // ---- MFMA: wave tile 16x64, K-step 64 (2 x K=32)
#pragma unroll
        for (int kk = 0; kk < 2; ++kk) {
            int rA = wm * 16 + lrow;
            int cA = kk * 4 + lq;
            bf16x8 a = *(const bf16x8*)((const char*)Aa + rA * 128 + ((cA ^ (rA & 7)) << 4));
#pragma unroll
            for (int nf = 0; nf < 4; ++nf) {
                int o = wn * 64 + nf * 16 + lrow;
                bf16x8 bb = *(const bf16x8*)((const char*)By + o * 128 + (((kk * 4 + lq) ^ (o & 7)) << 4));
                acc[nf] = __builtin_amdgcn_mfma_f32_16x16x32_bf16(a, bb, acc[nf], 0, 0, 0);
            }
        }
        __syncthreads();
    }

    // ---- degree reduction: thread t covered row t>>4 (pass 0) and 16+(t>>4) (pass 1)
    psums[t] = ps0;
    psums[256 + t] = ps1;
    __syncthreads();
    if (t < 32) {
        float s = 0.f;
        if (t < 16) {
#pragma unroll
            for (int j = 0; j < 16; ++j) s += psums[t * 16 + j];
        } else {
#pragma unroll
            for (int j = 0; j < 16; ++j) s += psums[256 + (t - 16) * 16 + j];
        }
        invdeg[t] = 1.0f / s;
    }
    __syncthreads();

    // ---- epilogue: scale by invdeg(row), + bias, leaky, fp32 store
#pragma unroll
    for (int nf = 0; nf < 4; ++nf) {
        int o = wn * 64 + nf * 16 + lrow;
        float bv = bias[o];
#pragma unroll
        for (int i = 0; i < 4; ++i) {
            int nl = wm * 16 + lq * 4 + i;
            float v = acc[nf][i] * invdeg[nl] + bv;
            v = (v >= 0.f) ? v : 0.01f * v;
            out[(((long)(b * 1024 + n0 + nl)) << 7) + o] = v;
        }
    }
}

extern "C" void kernel_launch(void* const* d_in, const int* in_sizes, int n_in,
                              void* d_out, int out_size, void* d_ws, size_t ws_size,
                              hipStream_t stream) {
    const float* node = (const float*)d_in[0];   // [16,1024,128]
    const float* adj  = (const float*)d_in[1];   // [16,1024,1024]
    const float* W    = (const float*)d_in[2];   // [128,128]
    const float* bias = (const float*)d_in[3];   // [128]
    float* out = (float*)d_out;                  // [16,1024,128]
    unsigned short* yT = (unsigned short*)d_ws;  // 16*128*1024 bf16 = 4 MB scratch

    k1_xw<<<dim3(512), dim3(256), 0, stream>>>(node, W, yT);
    k2_agg<<<dim3(512), dim3(256), 0, stream>>>(adj, yT, bias, out);
}